// Round 10
// baseline (449.889 us; speedup 1.0000x reference)
//
#include <hip/hip_runtime.h>
#include <math.h>

#define NB 16384
#define DD 1024
#define KF 5120

typedef unsigned short u16;
typedef unsigned int u32;
typedef __attribute__((ext_vector_type(8))) short bf16x8;
typedef __attribute__((ext_vector_type(4))) float f32x4;

// ---------- helpers ----------
__device__ __forceinline__ float bf2f(u16 u){
  return __uint_as_float(((unsigned)u) << 16);
}
__device__ __forceinline__ u16 f2bf(float f){
  unsigned u = __float_as_uint(f);
  return (u16)((u + 0x7fffu + ((u >> 16) & 1u)) >> 16);   // RNE
}
__device__ __forceinline__ u16 f2bf_tr(float f){
  return (u16)(__float_as_uint(f) >> 16);
}
__device__ __forceinline__ u32 pack2bf(float a, float b){
  return (u32)f2bf(a) | ((u32)f2bf(b) << 16);
}
__device__ __forceinline__ float fast_tanh(float x){
  float e = __expf(2.0f * x);
  return 1.0f - 2.0f * __builtin_amdgcn_rcpf(e + 1.0f);
}
__device__ __forceinline__ float wredsum(float x){
  #pragma unroll
  for(int o = 32; o >= 1; o >>= 1) x += __shfl_xor(x, o);
  return x;
}
__device__ __forceinline__ float wredmax(float x){
  #pragma unroll
  for(int o = 32; o >= 1; o >>= 1) x = fmaxf(x, __shfl_xor(x, o));
  return x;
}
__device__ __forceinline__ void gll16(const void* g, void* l){
  __builtin_amdgcn_global_load_lds(
      (const __attribute__((address_space(1))) u32*)g,
      (__attribute__((address_space(3))) u32*)l, 16, 0, 0);
}

// ---------- kpre: weight precompute (merged) ----------
__global__ __launch_bounds__(256) void kpre(
    const float* __restrict__ W1, const float* __restrict__ W2,
    const float* __restrict__ gamma, const float* __restrict__ beta,
    const float* __restrict__ l1W, const float* __restrict__ l1b,
    u16* __restrict__ Wb1, u16* __restrict__ W2T, u16* __restrict__ WpT,
    float* __restrict__ bp)
{
  __shared__ float red[4][64];
  int b = blockIdx.x, tid = threadIdx.x;
  if(b < 512){                                  // Wb1 (128 x 1024): [n][k]
    int idx = b*256 + tid;
    int n = idx >> 10, k = idx & 1023;
    float v = (n < 64) ? W1[(size_t)k*64 + n] : W1[(size_t)(1024+k)*64 + (n-64)];
    Wb1[idx] = f2bf(v);
  } else if(b < 768){                           // W2T (1024 x 64): [c][k]
    int idx = (b-512)*256 + tid;
    int c = idx >> 6, k = idx & 63;
    W2T[idx] = f2bf(W2[(size_t)k*DD + c]);
  } else if(b < 2048){                          // WpT (64 x 5120), BN folded
    int idx = (b-768)*256 + tid;
    int j = idx / KF, kk = idx - j*KF;
    const float gsc = 1.0f / sqrtf(1.0f + 1e-5f);
    int korig; float sc;
    if(kk < 1024){ korig = kk; sc = 1.f; }
    else if(kk < 4096){ korig = 1024 + ((kk - 1024) & 1023); sc = 1.0f/3.0f; }
    else { korig = 2048 + (kk - 4096); sc = 1.f; }
    float v = (j < 50) ? l1W[(size_t)korig*50 + j] * gamma[korig] * gsc * sc : 0.f;
    WpT[(size_t)j*KF + kk] = f2bf(v);
  } else {                                      // bp[j] = l1b[j] + beta @ l1W
    int j = tid & 63, seg = tid >> 6;
    float s = 0.f;
    if(j < 50){
      for(int k = seg*768; k < seg*768 + 768; k++)
        s = fmaf(beta[k], l1W[(size_t)k*50 + j], s);
    }
    red[seg][j] = s;
    __syncthreads();
    if(seg == 0){
      float t = red[0][j] + red[1][j] + red[2][j] + red[3][j];
      bp[j] = (j < 50) ? (l1b[j] + t) : 0.f;
    }
  }
}

// ---------- K1: per-row stats, w_uni, w_bi, uniB + xb ----------
__global__ __launch_bounds__(256) void k1_stats(
    const float* __restrict__ x, const float* __restrict__ attW,
    const float* __restrict__ attb, float* __restrict__ stats,
    u16* __restrict__ uniB, u16* __restrict__ xb, float* __restrict__ tw)
{
  int wave = threadIdx.x >> 6, lane = threadIdx.x & 63;
  int r = blockIdx.x * 4 + wave;
  const float2* xr  = (const float2*)(x + (size_t)r * 3 * DD);
  const float2* aw2 = (const float2*)attW;
  float2 a[8], v[8], l[8];
  float dA=0.f,dV=0.f,dL=0.f, mA=-1e30f,mV=-1e30f,mL=-1e30f;
  #pragma unroll
  for(int i = 0; i < 8; i++){
    int k2 = lane + i*64;
    a[i] = xr[k2]; v[i] = xr[512+k2]; l[i] = xr[1024+k2];
    float2 w = aw2[k2];
    dA = fmaf(a[i].x, w.x, fmaf(a[i].y, w.y, dA));
    dV = fmaf(v[i].x, w.x, fmaf(v[i].y, w.y, dV));
    dL = fmaf(l[i].x, w.x, fmaf(l[i].y, w.y, dL));
    mA = fmaxf(mA, fmaxf(a[i].x, a[i].y));
    mV = fmaxf(mV, fmaxf(v[i].x, v[i].y));
    mL = fmaxf(mL, fmaxf(l[i].x, l[i].y));
  }
  dA = wredsum(dA); dV = wredsum(dV); dL = wredsum(dL);
  mA = wredmax(mA); mV = wredmax(mV); mL = wredmax(mL);

  u32* xbw = (u32*)(xb + (size_t)3*r*DD);
  #pragma unroll
  for(int i = 0; i < 8; i++){
    int k2 = lane + i*64;
    xbw[k2]      = pack2bf(a[i].x, a[i].y);
    xbw[512+k2]  = pack2bf(v[i].x, v[i].y);
    xbw[1024+k2] = pack2bf(l[i].x, l[i].y);
  }

  float Sa=0.f,Sv=0.f,Sl=0.f,Eav=0.f,Eal=0.f,Evl=0.f;
  #pragma unroll
  for(int i = 0; i < 8; i++){
    float eax = __expf(a[i].x-mA), eay = __expf(a[i].y-mA);
    float evx = __expf(v[i].x-mV), evy = __expf(v[i].y-mV);
    float elx = __expf(l[i].x-mL), ely = __expf(l[i].y-mL);
    Sa += eax+eay; Sv += evx+evy; Sl += elx+ely;
    Eav += eax*evx + eay*evy; Eal += eax*elx + eay*ely; Evl += evx*elx + evy*ely;
  }
  Sa = wredsum(Sa); Sv = wredsum(Sv); Sl = wredsum(Sl);
  Eav = wredsum(Eav); Eal = wredsum(Eal); Evl = wredsum(Evl);

  float ab = attb[0];
  float ta = fast_tanh(dA + ab), tv = fast_tanh(dV + ab), tl = fast_tanh(dL + ab);
  float mm = fmaxf(ta, fmaxf(tv, tl));
  float e0 = __expf(ta-mm), e1 = __expf(tv-mm), e2 = __expf(tl-mm);
  float ss = e0 + e1 + e2;
  float sa = e0/ss, sv = e1/ss, sl = e2/ss;
  float dav = Eav/(Sa*Sv), dal = Eal/(Sa*Sl), dvl = Evl/(Sv*Sl);
  float sav = (sa+sv)/(dav+0.5f);
  float sal = (sa+sl)/(dal+0.5f);
  float svl = (sv+sl)/(dvl+0.5f);
  float m2 = fmaxf(sav, fmaxf(sal, svl));
  float f0 = __expf(sav-m2), f1 = __expf(sal-m2), f2 = __expf(svl-m2);
  float s2 = f0 + f1 + f2;
  float wb0 = f0/s2, wb1 = f1/s2, wb2 = f2/s2;

  if(lane == 0){
    float* st = stats + (size_t)r*24;
    st[0]=sa; st[1]=sv; st[2]=sl;
    st[3]=wb0; st[4]=wb1; st[5]=wb2;
    st[6]=sav; st[7]=sal; st[8]=svl;
    st[9]=mA; st[10]=Sa; st[11]=mV; st[12]=Sv; st[13]=mL; st[14]=Sl;
    float* twr = tw + (size_t)r*12;
    twr[0]=sa; twr[1]=sv; twr[2]=sl; twr[3]=wb0; twr[4]=wb1; twr[5]=wb2;
  }
  u32* uniw = (u32*)(uniB + (size_t)r*DD);
  #pragma unroll
  for(int i = 0; i < 8; i++){
    int k2 = lane + i*64;
    float ux = (sa*a[i].x + sv*v[i].x + sl*l[i].x) * (1.0f/3.0f);
    float uy = (sa*a[i].y + sv*v[i].y + sl*l[i].y) * (1.0f/3.0f);
    uniw[k2] = pack2bf(ux, uy);
  }
}

// ---------- layer-1 MFMA GEMM: (3NB,1024) @ Wb1^T -> UV1 (3NB x 128 fp32) ----------
__global__ __launch_bounds__(256) void kg1v3(
    const u16* __restrict__ src, const u16* __restrict__ Wb1,
    float* __restrict__ UV)
{
  __shared__ u16 Asm[2][64*64];   // 2 x 8KB
  int tid = threadIdx.x;
  int wv = tid >> 6, lane = tid & 63;
  int fr = lane & 15, kg = lane >> 4;
  int mb = blockIdx.x * 64;

  int r8 = lane >> 3, p = lane & 7;
  int sp = p ^ r8;
  int m0 = mb + (2*wv)*8 + r8;
  int m1 = mb + (2*wv+1)*8 + r8;
  const u16* gsrc0 = src + (size_t)m0*1024 + sp*8;
  const u16* gsrc1 = src + (size_t)m1*1024 + sp*8;

  f32x4 acc[4][2];
  #pragma unroll
  for(int rf = 0; rf < 4; rf++)
    #pragma unroll
    for(int nf = 0; nf < 2; nf++) acc[rf][nf] = (f32x4){0.f,0.f,0.f,0.f};

  gll16(gsrc0, &Asm[0][(2*wv)*512]);
  gll16(gsrc1, &Asm[0][(2*wv+1)*512]);
  __syncthreads();

  int buf = 0;
  for(int ci = 0; ci < 16; ci++){
    int k0 = ci*64;
    if(ci < 15){
      gll16(gsrc0 + k0 + 64, &Asm[buf^1][(2*wv)*512]);
      gll16(gsrc1 + k0 + 64, &Asm[buf^1][(2*wv+1)*512]);
    }
    #pragma unroll
    for(int ks = 0; ks < 2; ks++){
      bf16x8 a[4];
      #pragma unroll
      for(int rf = 0; rf < 4; rf++){
        int row = rf*16 + fr;
        int slot = (ks*4 + kg) ^ (row & 7);
        a[rf] = *(const bf16x8*)&Asm[buf][row*64 + slot*8];
      }
      #pragma unroll
      for(int nf = 0; nf < 2; nf++){
        int col = wv*32 + nf*16 + fr;
        bf16x8 b = *(const bf16x8*)&Wb1[(size_t)col*1024 + k0 + ks*32 + kg*8];
        #pragma unroll
        for(int rf = 0; rf < 4; rf++)
          acc[rf][nf] = __builtin_amdgcn_mfma_f32_16x16x32_bf16(a[rf], b, acc[rf][nf], 0, 0, 0);
      }
    }
    __syncthreads();
    buf ^= 1;
  }

  #pragma unroll
  for(int rf = 0; rf < 4; rf++)
    #pragma unroll
    for(int nf = 0; nf < 2; nf++)
      #pragma unroll
      for(int q = 0; q < 4; q++)
        UV[(size_t)(mb + rf*16 + kg*4 + q)*128 + wv*32 + nf*16 + fr] = acc[rf][nf][q];
}

// ---------- kBI: bimodal layer-2 + stats(w_tri) + UV2 GEMM + y1-bi, all fused ----------
// grid NB/16, 256 thr / 4 waves. Mids live only in LDS (Osm).
__global__ __launch_bounds__(256) void kBI(
    const float* __restrict__ UV1, const u16* __restrict__ xb,
    const u16* __restrict__ W2T, const u16* __restrict__ Wb1,
    const u16* __restrict__ WpT, const float* __restrict__ b1,
    const float* __restrict__ b2, float* __restrict__ stats,
    float* __restrict__ tw, float* __restrict__ UV2, float* __restrict__ y1g)
{
  __shared__ u16 Tsm[3][16][64];     // swizzled t fragments
  __shared__ u16 Osm[4][16][264];    // av, al, vl, sum (bf16, padded)
  __shared__ float stro[16][15];     // per-row stats[0..14]
  int tid = threadIdx.x;
  int wv = tid >> 6, lane = tid & 63;
  int fr = lane & 15, kg = lane >> 4;
  int Rb = blockIdx.x * 16;

  // phase 0: stats -> LDS
  if(tid < 240){
    int r = tid / 15, c = tid - r*15;
    stro[r][c] = stats[(size_t)(Rb + r)*24 + c];
  }
  // phase 1: t-build (3 pairs x 16 rows x 64)
  for(int i = tid; i < 384; i += 256){
    int g = i & 7, r = (i >> 3) & 15, p = i >> 7;
    int R = Rb + r;
    int up = (p == 2) ? 1 : 0;
    int vp = (p == 0) ? 1 : 2;
    const float* Up = UV1 + (size_t)(3*R + up)*128 + g*8;
    const float* Vp = UV1 + (size_t)(3*R + vp)*128 + 64 + g*8;
    float4 u0 = *(const float4*)Up, u1 = *(const float4*)(Up+4);
    float4 v0 = *(const float4*)Vp, v1 = *(const float4*)(Vp+4);
    float4 bb0 = *(const float4*)(b1 + g*8), bb1 = *(const float4*)(b1 + g*8 + 4);
    float t[8] = {u0.x+v0.x+bb0.x, u0.y+v0.y+bb0.y, u0.z+v0.z+bb0.z, u0.w+v0.w+bb0.w,
                  u1.x+v1.x+bb1.x, u1.y+v1.y+bb1.y, u1.z+v1.z+bb1.z, u1.w+v1.w+bb1.w};
    bf16x8 o;
    #pragma unroll
    for(int j = 0; j < 8; j++){
      float tv = t[j] > 0.f ? t[j] : 0.2f*t[j];
      o[j] = (short)f2bf_tr(tv);
    }
    *(bf16x8*)&Tsm[p][r][(g ^ (r & 7))*8] = o;
  }
  __syncthreads();

  // persistent accumulators
  f32x4 acc_uv[3][2];
  #pragma unroll
  for(int p = 0; p < 3; p++){ acc_uv[p][0] = (f32x4){0,0,0,0}; acc_uv[p][1] = (f32x4){0,0,0,0}; }
  f32x4 accy = (f32x4){0,0,0,0};
  // per-thread stats partials, row = tid>>4
  int srow = tid >> 4, sc0 = (tid & 15) * 16;
  float SP[9] = {0,0,0,0,0,0,0,0,0};   // Savv,Sall,Svll,E1..E6
  float mAr = stro[srow][9],  Sar = stro[srow][10];
  float mVr = stro[srow][11], Svr = stro[srow][12];
  float mLr = stro[srow][13], Slr = stro[srow][14];
  size_t xbase = (size_t)3*(Rb + srow)*DD;

  for(int cg = 0; cg < 4; cg++){
    // mids MFMA (reads Tsm, W2T only)
    f32x4 acc[3][4];
    #pragma unroll
    for(int p = 0; p < 3; p++)
      #pragma unroll
      for(int cf = 0; cf < 4; cf++) acc[p][cf] = (f32x4){0,0,0,0};
    #pragma unroll
    for(int ks = 0; ks < 2; ks++){
      bf16x8 a[3];
      #pragma unroll
      for(int p = 0; p < 3; p++)
        a[p] = *(const bf16x8*)&Tsm[p][fr][(((ks<<2)+kg) ^ (fr & 7))*8];
      #pragma unroll
      for(int cf = 0; cf < 4; cf++){
        bf16x8 b = *(const bf16x8*)&W2T[(size_t)(cg*256 + wv*64 + cf*16 + fr)*64
                                        + ks*32 + kg*8];
        #pragma unroll
        for(int p = 0; p < 3; p++)
          acc[p][cf] = __builtin_amdgcn_mfma_f32_16x16x32_bf16(a[p], b, acc[p][cf], 0, 0, 0);
      }
    }
    __syncthreads();   // previous cg's Osm readers done
    // epilogue -> Osm
    #pragma unroll
    for(int q = 0; q < 4; q++){
      int row = kg*4 + q;
      #pragma unroll
      for(int cf = 0; cf < 4; cf++){
        int cloc = wv*64 + cf*16 + fr;
        float b2c = b2[cg*256 + cloc];
        float sm = 0.f;
        #pragma unroll
        for(int p = 0; p < 3; p++){
          float g = stro[row][3+p] * fast_tanh(acc[p][cf][q] + b2c);
          float val = g > 0.f ? g : 0.01f*g;
          Osm[p][row][cloc] = f2bf(val);
          sm += val;
        }
        Osm[3][row][cloc] = f2bf_tr(sm);
      }
    }
    __syncthreads();

    // (a) stats partials from Osm + xb
    {
      const u32* xa1 = (const u32*)(xb + xbase + cg*256 + sc0);
      const u32* xv1 = (const u32*)(xb + xbase + DD + cg*256 + sc0);
      const u32* xl1 = (const u32*)(xb + xbase + 2*DD + cg*256 + sc0);
      #pragma unroll
      for(int j = 0; j < 8; j++){
        u32 oav = *(const u32*)&Osm[0][srow][sc0 + 2*j];
        u32 oal = *(const u32*)&Osm[1][srow][sc0 + 2*j];
        u32 ovl = *(const u32*)&Osm[2][srow][sc0 + 2*j];
        u32 wa = xa1[j], wvv = xv1[j], wl = xl1[j];
        float eavx = __expf(bf2f((u16)oav)), eavy = __expf(bf2f((u16)(oav>>16)));
        float ealx = __expf(bf2f((u16)oal)), ealy = __expf(bf2f((u16)(oal>>16)));
        float evlx = __expf(bf2f((u16)ovl)), evly = __expf(bf2f((u16)(ovl>>16)));
        float eax = __expf(bf2f((u16)wa)-mAr),  eay = __expf(bf2f((u16)(wa>>16))-mAr);
        float evx = __expf(bf2f((u16)wvv)-mVr), evy = __expf(bf2f((u16)(wvv>>16))-mVr);
        float elx = __expf(bf2f((u16)wl)-mLr),  ely = __expf(bf2f((u16)(wl>>16))-mLr);
        SP[0] += eavx+eavy; SP[1] += ealx+ealy; SP[2] += evlx+evly;
        SP[3] += eavx*evlx + eavy*evly;
        SP[4] += eavx*ealx + eavy*ealy;
        SP[5] += ealx*evlx + ealy*evly;
        SP[6] += eavx*elx + eavy*ely;
        SP[7] += ealx*evx + ealy*evy;
        SP[8] += evlx*eax + evly*eay;
      }
    }
    // (b) UV2 K-accumulate: Osm mids @ Wb1 slice
    #pragma unroll
    for(int ks8 = 0; ks8 < 8; ks8++){
      bf16x8 a[3];
      #pragma unroll
      for(int p = 0; p < 3; p++)
        a[p] = *(const bf16x8*)&Osm[p][fr][ks8*32 + kg*8];
      #pragma unroll
      for(int nf = 0; nf < 2; nf++){
        int n = wv*32 + nf*16 + fr;
        bf16x8 b = *(const bf16x8*)&Wb1[(size_t)n*1024 + cg*256 + ks8*32 + kg*8];
        #pragma unroll
        for(int p = 0; p < 3; p++)
          acc_uv[p][nf] = __builtin_amdgcn_mfma_f32_16x16x32_bf16(a[p], b, acc_uv[p][nf], 0, 0, 0);
      }
    }
    // (c) y1 bimodal-sum K-accumulate
    #pragma unroll
    for(int kq = 0; kq < 4; kq++)
      #pragma unroll
      for(int ks = 0; ks < 2; ks++){
        bf16x8 a = *(const bf16x8*)&Osm[3][fr][kq*64 + ks*32 + kg*8];
        bf16x8 b = *(const bf16x8*)&WpT[(size_t)(wv*16 + fr)*KF + 1024 + cg*256
                                        + kq*64 + ks*32 + kg*8];
        accy = __builtin_amdgcn_mfma_f32_16x16x32_bf16(a, b, accy, 0, 0, 0);
      }
  }

  // UV2 store (full K done; plain stores)
  #pragma unroll
  for(int p = 0; p < 3; p++)
    #pragma unroll
    for(int nf = 0; nf < 2; nf++)
      #pragma unroll
      for(int q = 0; q < 4; q++)
        UV2[(size_t)(3*(Rb + kg*4 + q) + p)*128 + wv*32 + nf*16 + fr] = acc_uv[p][nf][q];
  // y1g plain store (first writer; no zeroing needed)
  #pragma unroll
  for(int q = 0; q < 4; q++)
    y1g[(size_t)(Rb + kg*4 + q)*64 + wv*16 + fr] = accy[q];

  // stats finalize: reduce SP across the 16 threads of each row
  #pragma unroll
  for(int s = 0; s < 9; s++){
    SP[s] += __shfl_xor(SP[s], 1);
    SP[s] += __shfl_xor(SP[s], 2);
    SP[s] += __shfl_xor(SP[s], 4);
    SP[s] += __shfl_xor(SP[s], 8);
  }
  if((tid & 15) == 0){
    int r = srow;
    float sa=stro[r][0], sv=stro[r][1], sl=stro[r][2];
    float sav=stro[r][6], sal=stro[r][7], svl=stro[r][8];
    float d1 = SP[3]/(SP[0]*SP[2]), d2 = SP[4]/(SP[0]*SP[1]), d3 = SP[5]/(SP[1]*SP[2]);
    float d4 = SP[6]/(SP[0]*Slr),   d5 = SP[7]/(SP[1]*Svr),   d6 = SP[8]/(SP[2]*Sar);
    float t0 = (sav+svl)/(d1+0.5f);
    float t1 = (sav+sal)/(d2+0.5f);
    float t2 = (sal+svl)/(d3+0.5f);
    float t3 = (sav+sl)/(d4+0.5f);
    float t4 = (sal+sv)/(d5+0.5f);
    float t5 = (sa+svl)/(d6+0.5f);
    float mx = fmaxf(fmaxf(fmaxf(t0,t1),fmaxf(t2,t3)),fmaxf(t4,t5));
    float g0=__expf(t0-mx),g1=__expf(t1-mx),g2=__expf(t2-mx);
    float g3=__expf(t3-mx),g4=__expf(t4-mx),g5=__expf(t5-mx);
    float gs = g0+g1+g2+g3+g4+g5;
    float wt[6] = {g0/gs,g1/gs,g2/gs,g3/gs,g4/gs,g5/gs};
    float* st = stats + (size_t)(Rb + r)*24;
    float* twr = tw + (size_t)(Rb + r)*12;
    #pragma unroll
    for(int p = 0; p < 6; p++){ st[15+p] = wt[p]; twr[6+p] = wt[p]; }
  }
}

// ---------- kTRI: trimodal layer-2 + y1-tri, full-K per block ----------
// grid NB/16; y1g plain RMW (unique writer per row, after kBI).
__global__ __launch_bounds__(256) void kTRI(
    const float* __restrict__ UV2, const float* __restrict__ UV1,
    const u16* __restrict__ W2T, const u16* __restrict__ WpT,
    const float* __restrict__ b1, const float* __restrict__ b2,
    const float* __restrict__ stats, float* __restrict__ y1g)
{
  __shared__ u16 Tsm[6][16][64];
  __shared__ u16 Osm[16][264];
  __shared__ float stw[16][6];
  int tid = threadIdx.x;
  int wv = tid >> 6, lane = tid & 63;
  int fr = lane & 15, kg = lane >> 4;
  int Rb = blockIdx.x * 16;

  if(tid < 96){
    int r = tid / 6, p = tid - r*6;
    stw[r][p] = stats[(size_t)(Rb + r)*24 + 15 + p];
  }
  for(int i = tid; i < 768; i += 256){
    int g = i & 7, r = (i >> 3) & 15, p = i >> 7;
    int R = Rb + r;
    int up = (0x210200 >> (p*4)) & 15;
    int vp = (0x012112 >> (p*4)) & 15;
    const float* VB = (p < 3) ? UV2 : UV1;
    const float* Up = UV2 + (size_t)(3*R + up)*128 + g*8;
    const float* Vp = VB  + (size_t)(3*R + vp)*128 + 64 + g*8;
    float4 u0 = *(const float4*)Up, u1 = *(const float4*)(Up+4);
    float4 v0 = *(const float4*)Vp, v1 = *(const float4*)(Vp+4);
    float4 bb0 = *(const float4*)(b1 + g*8), bb1 = *(const float4*)(b1 + g*8 + 4);
    float t[8] = {u0.x+v0.x+bb0.x, u0.y+v0.y+bb0.y, u0.z+v0.z+bb0.z, u0.w+v0.w+bb0.w,
                  u1.x+v1.x+bb1.x, u1.y+v1.y+bb1.y, u1.z+v1.z+bb1.z, u1.w+v1.w+bb1.w};
    bf16x8 o;
    #pragma unroll
    for(int j = 0; j < 8; j++){
      float tv = t[j] > 0.f ? t[j] : 0.2f*t[j];
      o[j] = (short)f2bf_tr(tv);
    }
    *(bf16x8*)&Tsm[p][r][(g ^ (r & 7))*8] = o;
  }
  __syncthreads();

  f32x4 accy = (f32x4){0,0,0,0};
  for(int cg = 0; cg < 4; cg++){
    f32x4 acc[6][4];
    #pragma unroll
    for(int p = 0; p < 6; p++)
      #pragma unroll
      for(int cf = 0; cf < 4; cf++) acc[p][cf] = (f32x4){0,0,0,0};
    #pragma unroll
    for(int ks = 0; ks < 2; ks++){
      bf16x8 a[6];
      #pragma unroll
      for(int p = 0; p < 6; p++)
        a[p] = *(const bf16x8*)&Tsm[p][fr][(((ks<<2)+kg) ^ (fr & 7))*8];
      #pragma unroll
      for(int cf = 0; cf < 4; cf++){
        bf16x8 b = *(const bf16x8*)&W2T[(size_t)(cg*256 + wv*64 + cf*16 + fr)*64
                                        + ks*32 + kg*8];
        #pragma unroll
        for(int p = 0; p < 6; p++)
          acc[p][cf] = __builtin_amdgcn_mfma_f32_16x16x32_bf16(a[p], b, acc[p][cf], 0, 0, 0);
      }
    }
    __syncthreads();
    #pragma unroll
    for(int q = 0; q < 4; q++){
      int row = kg*4 + q;
      #pragma unroll
      for(int cf = 0; cf < 4; cf++){
        int cloc = wv*64 + cf*16 + fr;
        float b2c = b2[cg*256 + cloc];
        float s = 0.f;
        #pragma unroll
        for(int p = 0; p < 6; p++){
          float g = stw[row][p] * fast_tanh(acc[p][cf][q] + b2c);
          s += g > 0.f ? g : 0.01f*g;
        }
        Osm[row][cloc] = f2bf_tr(s * (1.0f/6.0f));
      }
    }
    __syncthreads();
    #pragma unroll
    for(int kq = 0; kq < 4; kq++)
      #pragma unroll
      for(int ks = 0; ks < 2; ks++){
        bf16x8 a = *(const bf16x8*)&Osm[fr][kq*64 + ks*32 + kg*8];
        bf16x8 b = *(const bf16x8*)&WpT[(size_t)(wv*16 + fr)*KF + 4096 + cg*256
                                        + kq*64 + ks*32 + kg*8];
        accy = __builtin_amdgcn_mfma_f32_16x16x32_bf16(a, b, accy, 0, 0, 0);
      }
  }
  #pragma unroll
  for(int q = 0; q < 4; q++){
    size_t idx = (size_t)(Rb + kg*4 + q)*64 + wv*16 + fr;
    y1g[idx] += accy[q];
  }
}

// ---------- K6 v5: uni GEMM (K=1024) + y1g + MLP tail ----------
__global__ __launch_bounds__(256) void k6v5(
    const u16* __restrict__ uniB, const u16* __restrict__ WpT,
    const float* __restrict__ y1g, const float* __restrict__ bp,
    const float* __restrict__ l2W, const float* __restrict__ l2b,
    const float* __restrict__ l3W, const float* __restrict__ l3b,
    float* __restrict__ y2out)
{
  __shared__ __align__(16) char smem[37952];
  u16*  Asm = (u16*)smem;
  float* W2s = (float*)(smem + 16384);
  float* W3s = (float*)(smem + 16384 + 12800);
  float* Ys  = (float*)smem;
  float* Ys2 = (float*)(smem + 16384 + 12800 + 1600);

  int tid = threadIdx.x;
  int wv = tid >> 6, lane = tid & 63;
  int fr = lane & 15, kg = lane >> 4;
  int rb = blockIdx.x * 32;

  for(int t = tid; t < 3200; t += 256){
    int c = t & 63;
    W2s[t] = (c < 50) ? l2W[(t >> 6)*50 + c] : 0.f;
  }
  for(int t = tid; t < 400; t += 256) W3s[t] = l3W[t];

  int r8 = lane >> 3, pp = lane & 7;
  int sp = pp ^ r8;
  const u16* gsrc = uniB + (size_t)(rb + wv*8 + r8)*DD + sp*8;
  const u16* bptr = WpT  + (size_t)(wv*16 + fr)*KF + kg*8;

  f32x4 acc[2];
  acc[0] = (f32x4){0.f,0.f,0.f,0.f};
  acc[1] = (f32x4){0.f,0.f,0.f,0.f};

  gll16(gsrc,      &Asm[wv*1024]);
  gll16(gsrc + 64, &Asm[wv*1024 + 512]);
  __syncthreads();

  int buf = 0;
  for(int ci = 0; ci < 8; ci++){
    int k0 = ci*128;
    if(ci < 7){
      gll16(gsrc + k0 + 128, &Asm[(buf^1)*4096 + wv*1024]);
      gll16(gsrc + k0 + 192, &Asm[(buf^1)*4096 + wv*1024 + 512]);
    }
    #pragma unroll
    for(int kh = 0; kh < 2; kh++){
      #pragma unroll
      for(int ks = 0; ks < 2; ks++){
        bf16x8 b = *(const bf16x8*)(bptr + k0 + kh*64 + ks*32);
        #pragma unroll
        for(int rf = 0; rf < 2; rf++){
          int row = rf*16 + fr;
          int slot = ((ks<<2) + kg) ^ (row & 7);
          bf16x8 a = *(const bf16x8*)&Asm[buf*4096 + (row>>3)*1024 + kh*512
                                          + (row & 7)*64 + slot*8];
          acc[rf] = __builtin_amdgcn_mfma_f32_16x16x32_bf16(a, b, acc[rf], 0, 0, 0);
        }
      }
    }
    __syncthreads();
    buf ^= 1;
  }

  {
    int col = wv*16 + fr;
    float bpc = bp[col];
    #pragma unroll
    for(int rf = 0; rf < 2; rf++)
      #pragma unroll
      for(int q = 0; q < 4; q++){
        int row = rf*16 + kg*4 + q;
        if(col < 50){
          float z = acc[rf][q] + y1g[(size_t)(rb + row)*64 + col] + bpc;
          Ys[row*56 + col] = fast_tanh(z);
        }
      }
  }
  __syncthreads();

  {
    int r = tid >> 3, cg = (tid & 7) * 7;
    float a2[7] = {0,0,0,0,0,0,0};
    for(int k = 0; k < 50; k++){
      float yv = Ys[r*56 + k];
      #pragma unroll
      for(int c = 0; c < 7; c++) a2[c] = fmaf(yv, W2s[k*64 + cg + c], a2[c]);
    }
    #pragma unroll
    for(int c = 0; c < 7; c++){
      int cc = cg + c;
      if(cc < 50) Ys2[r*56 + cc] = fast_tanh(a2[c] + l2b[cc]);
    }
  }
  __syncthreads();

  {
    int r = tid >> 3, c = tid & 7;
    float z = l3b[c];
    for(int k = 0; k < 50; k++) z = fmaf(Ys2[r*56 + k], W3s[k*8 + c], z);
    float m = z;
    m = fmaxf(m, __shfl_xor(m, 1));
    m = fmaxf(m, __shfl_xor(m, 2));
    m = fmaxf(m, __shfl_xor(m, 4));
    float e = __expf(z - m);
    float s = e;
    s += __shfl_xor(s, 1); s += __shfl_xor(s, 2); s += __shfl_xor(s, 4);
    y2out[(size_t)(rb + r)*8 + c] = e / s;
  }
}

// ---------- launch ----------
extern "C" void kernel_launch(void* const* d_in, const int* in_sizes, int n_in,
                              void* d_out, int out_size, void* d_ws, size_t ws_size,
                              hipStream_t stream)
{
  (void)in_sizes; (void)n_in; (void)out_size; (void)ws_size;
  const float* x    = (const float*)d_in[0];
  const float* attW = (const float*)d_in[1];
  const float* attb = (const float*)d_in[2];
  const float* gfW1 = (const float*)d_in[3];
  const float* gfb1 = (const float*)d_in[4];
  const float* gfW2 = (const float*)d_in[5];
  const float* gfb2 = (const float*)d_in[6];
  const float* bng  = (const float*)d_in[7];
  const float* bnb  = (const float*)d_in[8];
  const float* l1W  = (const float*)d_in[9];
  const float* l1b  = (const float*)d_in[10];
  const float* l2W  = (const float*)d_in[11];
  const float* l2b  = (const float*)d_in[12];
  const float* l3W  = (const float*)d_in[13];
  const float* l3b  = (const float*)d_in[14];

  float* out = (float*)d_out;
  float* tw  = out + (size_t)NB*8;

  // workspace layout (~185 MB)
  float* ws    = (float*)d_ws;
  float* stats = ws;                               // NB*24 f32
  float* UV1   = stats + (size_t)NB*24;            // 3*NB*128 f32
  float* UV2   = UV1 + (size_t)3*NB*128;           // 3*NB*128 f32
  float* bp    = UV2 + (size_t)3*NB*128;           // 64 f32
  float* y1g   = bp + 64;                          // NB*64 f32
  u16* WpT     = (u16*)(y1g + (size_t)NB*64);      // 64*KF bf16
  u16* Wb1     = WpT + (size_t)64*KF;              // 128*1024 bf16
  u16* W2T     = Wb1 + (size_t)128*1024;           // 1024*64 bf16
  u16* xb      = W2T + (size_t)1024*64;            // 3*NB*1024 bf16
  u16* uniB    = xb + (size_t)3*NB*DD;             // NB*1024 bf16

  kpre<<<dim3(2049), dim3(256), 0, stream>>>(gfW1, gfW2, bng, bnb, l1W, l1b,
                                             Wb1, W2T, WpT, bp);
  k1_stats<<<dim3(NB/4), dim3(256), 0, stream>>>(x, attW, attb, stats, uniB, xb, tw);
  kg1v3<<<dim3(3*NB/64), dim3(256), 0, stream>>>(xb, Wb1, UV1);
  kBI<<<dim3(NB/16), dim3(256), 0, stream>>>(UV1, xb, W2T, Wb1, WpT,
                                             gfb1, gfb2, stats, tw, UV2, y1g);
  kTRI<<<dim3(NB/16), dim3(256), 0, stream>>>(UV2, UV1, W2T, WpT,
                                              gfb1, gfb2, stats, y1g);
  k6v5<<<dim3(NB/32), dim3(256), 0, stream>>>(uniB, WpT, y1g, bp,
                                              l2W, l2b, l3W, l3b, out);
}

// Round 11
// 379.876 us; speedup vs baseline: 1.1843x; 1.1843x over previous
//
#include <hip/hip_runtime.h>
#include <math.h>

#define NB 16384
#define DD 1024
#define KF 5120

typedef unsigned short u16;
typedef unsigned int u32;
typedef __attribute__((ext_vector_type(8))) short bf16x8;
typedef __attribute__((ext_vector_type(4))) float f32x4;

// ---------- helpers ----------
__device__ __forceinline__ float bf2f(u16 u){
  return __uint_as_float(((unsigned)u) << 16);
}
__device__ __forceinline__ u16 f2bf(float f){
  unsigned u = __float_as_uint(f);
  return (u16)((u + 0x7fffu + ((u >> 16) & 1u)) >> 16);   // RNE
}
__device__ __forceinline__ u16 f2bf_tr(float f){
  return (u16)(__float_as_uint(f) >> 16);
}
__device__ __forceinline__ u32 pack2bf(float a, float b){
  return (u32)f2bf(a) | ((u32)f2bf(b) << 16);
}
__device__ __forceinline__ float fast_tanh(float x){
  float e = __expf(2.0f * x);
  return 1.0f - 2.0f * __builtin_amdgcn_rcpf(e + 1.0f);
}
__device__ __forceinline__ float wredsum(float x){
  #pragma unroll
  for(int o = 32; o >= 1; o >>= 1) x += __shfl_xor(x, o);
  return x;
}
__device__ __forceinline__ float wredmax(float x){
  #pragma unroll
  for(int o = 32; o >= 1; o >>= 1) x = fmaxf(x, __shfl_xor(x, o));
  return x;
}
__device__ __forceinline__ void gll16(const void* g, void* l){
  __builtin_amdgcn_global_load_lds(
      (const __attribute__((address_space(1))) u32*)g,
      (__attribute__((address_space(3))) u32*)l, 16, 0, 0);
}

// ---------- kpre: weight precompute + y1g/spart zero (merged) ----------
__global__ __launch_bounds__(256) void kpre(
    const float* __restrict__ W1, const float* __restrict__ W2,
    const float* __restrict__ gamma, const float* __restrict__ beta,
    const float* __restrict__ l1W, const float* __restrict__ l1b,
    u16* __restrict__ Wb1, u16* __restrict__ W2T, u16* __restrict__ WpT,
    float* __restrict__ bp, float* __restrict__ y1g, float* __restrict__ spart)
{
  __shared__ float red[4][64];
  int b = blockIdx.x, tid = threadIdx.x;
  if(b < 512){                                  // Wb1 (128 x 1024): [n][k]
    int idx = b*256 + tid;
    int n = idx >> 10, k = idx & 1023;
    float v = (n < 64) ? W1[(size_t)k*64 + n] : W1[(size_t)(1024+k)*64 + (n-64)];
    Wb1[idx] = f2bf(v);
  } else if(b < 768){                           // W2T (1024 x 64): [c][k]
    int idx = (b-512)*256 + tid;
    int c = idx >> 6, k = idx & 63;
    W2T[idx] = f2bf(W2[(size_t)k*DD + c]);
  } else if(b < 2048){                          // WpT (64 x 5120), BN folded
    int idx = (b-768)*256 + tid;
    int j = idx / KF, kk = idx - j*KF;
    const float gsc = 1.0f / sqrtf(1.0f + 1e-5f);
    int korig; float sc;
    if(kk < 1024){ korig = kk; sc = 1.f; }
    else if(kk < 4096){ korig = 1024 + ((kk - 1024) & 1023); sc = 1.0f/3.0f; }
    else { korig = 2048 + (kk - 4096); sc = 1.f; }
    float v = (j < 50) ? l1W[(size_t)korig*50 + j] * gamma[korig] * gsc * sc : 0.f;
    WpT[(size_t)j*KF + kk] = f2bf(v);
  } else if(b < 3072){                          // zero y1g (NB*64 f32)
    int idx = (b - 2048)*256 + tid;
    ((float4*)y1g)[idx] = make_float4(0.f,0.f,0.f,0.f);
  } else if(b < 3216){                          // zero spart (NB*9 f32)
    int idx = (b - 3072)*256 + tid;
    ((float4*)spart)[idx] = make_float4(0.f,0.f,0.f,0.f);
  } else {                                      // bp[j] = l1b[j] + beta @ l1W
    int j = tid & 63, seg = tid >> 6;
    float s = 0.f;
    if(j < 50){
      for(int k = seg*768; k < seg*768 + 768; k++)
        s = fmaf(beta[k], l1W[(size_t)k*50 + j], s);
    }
    red[seg][j] = s;
    __syncthreads();
    if(seg == 0){
      float t = red[0][j] + red[1][j] + red[2][j] + red[3][j];
      bp[j] = (j < 50) ? (l1b[j] + t) : 0.f;
    }
  }
}

// ---------- K1: per-row stats, w_uni, w_bi, uniB + xb (float4) ----------
__global__ __launch_bounds__(256) void k1_stats(
    const float* __restrict__ x, const float* __restrict__ attW,
    const float* __restrict__ attb, float* __restrict__ stats,
    u16* __restrict__ uniB, u16* __restrict__ xb, float* __restrict__ tw)
{
  int wave = threadIdx.x >> 6, lane = threadIdx.x & 63;
  int r = blockIdx.x * 4 + wave;
  const float4* xr  = (const float4*)(x + (size_t)r * 3 * DD);
  const float4* aw4 = (const float4*)attW;
  float4 a[4], v[4], l[4];
  float dA=0.f,dV=0.f,dL=0.f, mA=-1e30f,mV=-1e30f,mL=-1e30f;
  #pragma unroll
  for(int i = 0; i < 4; i++){
    int k4 = lane + i*64;
    a[i] = xr[k4]; v[i] = xr[256+k4]; l[i] = xr[512+k4];
    float4 w = aw4[k4];
    dA = fmaf(a[i].x,w.x, fmaf(a[i].y,w.y, fmaf(a[i].z,w.z, fmaf(a[i].w,w.w, dA))));
    dV = fmaf(v[i].x,w.x, fmaf(v[i].y,w.y, fmaf(v[i].z,w.z, fmaf(v[i].w,w.w, dV))));
    dL = fmaf(l[i].x,w.x, fmaf(l[i].y,w.y, fmaf(l[i].z,w.z, fmaf(l[i].w,w.w, dL))));
    mA = fmaxf(mA, fmaxf(fmaxf(a[i].x,a[i].y), fmaxf(a[i].z,a[i].w)));
    mV = fmaxf(mV, fmaxf(fmaxf(v[i].x,v[i].y), fmaxf(v[i].z,v[i].w)));
    mL = fmaxf(mL, fmaxf(fmaxf(l[i].x,l[i].y), fmaxf(l[i].z,l[i].w)));
  }
  dA = wredsum(dA); dV = wredsum(dV); dL = wredsum(dL);
  mA = wredmax(mA); mV = wredmax(mV); mL = wredmax(mL);

  uint2* xbw = (uint2*)(xb + (size_t)3*r*DD);
  #pragma unroll
  for(int i = 0; i < 4; i++){
    int k4 = lane + i*64;
    xbw[k4]     = make_uint2(pack2bf(a[i].x,a[i].y), pack2bf(a[i].z,a[i].w));
    xbw[256+k4] = make_uint2(pack2bf(v[i].x,v[i].y), pack2bf(v[i].z,v[i].w));
    xbw[512+k4] = make_uint2(pack2bf(l[i].x,l[i].y), pack2bf(l[i].z,l[i].w));
  }

  float Sa=0.f,Sv=0.f,Sl=0.f,Eav=0.f,Eal=0.f,Evl=0.f;
  #pragma unroll
  for(int i = 0; i < 4; i++){
    float ea0=__expf(a[i].x-mA), ea1=__expf(a[i].y-mA), ea2=__expf(a[i].z-mA), ea3=__expf(a[i].w-mA);
    float ev0=__expf(v[i].x-mV), ev1=__expf(v[i].y-mV), ev2=__expf(v[i].z-mV), ev3=__expf(v[i].w-mV);
    float el0=__expf(l[i].x-mL), el1=__expf(l[i].y-mL), el2=__expf(l[i].z-mL), el3=__expf(l[i].w-mL);
    Sa += ea0+ea1+ea2+ea3; Sv += ev0+ev1+ev2+ev3; Sl += el0+el1+el2+el3;
    Eav += ea0*ev0 + ea1*ev1 + ea2*ev2 + ea3*ev3;
    Eal += ea0*el0 + ea1*el1 + ea2*el2 + ea3*el3;
    Evl += ev0*el0 + ev1*el1 + ev2*el2 + ev3*el3;
  }
  Sa = wredsum(Sa); Sv = wredsum(Sv); Sl = wredsum(Sl);
  Eav = wredsum(Eav); Eal = wredsum(Eal); Evl = wredsum(Evl);

  float ab = attb[0];
  float ta = fast_tanh(dA + ab), tv = fast_tanh(dV + ab), tl = fast_tanh(dL + ab);
  float mm = fmaxf(ta, fmaxf(tv, tl));
  float e0 = __expf(ta-mm), e1 = __expf(tv-mm), e2 = __expf(tl-mm);
  float ss = e0 + e1 + e2;
  float sa = e0/ss, sv = e1/ss, sl = e2/ss;
  float dav = Eav/(Sa*Sv), dal = Eal/(Sa*Sl), dvl = Evl/(Sv*Sl);
  float sav = (sa+sv)/(dav+0.5f);
  float sal = (sa+sl)/(dal+0.5f);
  float svl = (sv+sl)/(dvl+0.5f);
  float m2 = fmaxf(sav, fmaxf(sal, svl));
  float f0 = __expf(sav-m2), f1 = __expf(sal-m2), f2 = __expf(svl-m2);
  float s2 = f0 + f1 + f2;
  float wb0 = f0/s2, wb1 = f1/s2, wb2 = f2/s2;

  if(lane == 0){
    float* st = stats + (size_t)r*24;
    st[0]=sa; st[1]=sv; st[2]=sl;
    st[3]=wb0; st[4]=wb1; st[5]=wb2;
    st[6]=sav; st[7]=sal; st[8]=svl;
    st[9]=mA; st[10]=Sa; st[11]=mV; st[12]=Sv; st[13]=mL; st[14]=Sl;
    float* twr = tw + (size_t)r*12;
    twr[0]=sa; twr[1]=sv; twr[2]=sl; twr[3]=wb0; twr[4]=wb1; twr[5]=wb2;
  }
  uint2* uniw = (uint2*)(uniB + (size_t)r*DD);
  #pragma unroll
  for(int i = 0; i < 4; i++){
    int k4 = lane + i*64;
    float u0 = (sa*a[i].x + sv*v[i].x + sl*l[i].x) * (1.0f/3.0f);
    float u1 = (sa*a[i].y + sv*v[i].y + sl*l[i].y) * (1.0f/3.0f);
    float u2 = (sa*a[i].z + sv*v[i].z + sl*l[i].z) * (1.0f/3.0f);
    float u3 = (sa*a[i].w + sv*v[i].w + sl*l[i].w) * (1.0f/3.0f);
    uniw[k4] = make_uint2(pack2bf(u0,u1), pack2bf(u2,u3));
  }
}

// ---------- layer-1 MFMA GEMM: (3NB,1024) @ Wb1^T -> UV (3NB x 128 fp32) ----------
template<int FCAT>
__global__ __launch_bounds__(256) void kg1v3(
    const u16* __restrict__ src, const u16* __restrict__ Wb1,
    float* __restrict__ UV)
{
  __shared__ u16 Asm[2][64*64];   // 2 x 8KB
  int tid = threadIdx.x;
  int wv = tid >> 6, lane = tid & 63;
  int fr = lane & 15, kg = lane >> 4;
  int mb = blockIdx.x * 64;

  int r8 = lane >> 3, p = lane & 7;
  int sp = p ^ r8;
  int m0 = mb + (2*wv)*8 + r8;
  int m1 = mb + (2*wv+1)*8 + r8;
  size_t b0, b1;
  if(FCAT){
    int R0 = m0/3, R1 = m1/3;
    b0 = (size_t)R0*KF + (size_t)(1 + (m0 - 3*R0))*1024;
    b1 = (size_t)R1*KF + (size_t)(1 + (m1 - 3*R1))*1024;
  } else {
    b0 = (size_t)m0*1024;
    b1 = (size_t)m1*1024;
  }
  const u16* gsrc0 = src + b0 + sp*8;
  const u16* gsrc1 = src + b1 + sp*8;

  f32x4 acc[4][2];
  #pragma unroll
  for(int rf = 0; rf < 4; rf++)
    #pragma unroll
    for(int nf = 0; nf < 2; nf++) acc[rf][nf] = (f32x4){0.f,0.f,0.f,0.f};

  gll16(gsrc0, &Asm[0][(2*wv)*512]);
  gll16(gsrc1, &Asm[0][(2*wv+1)*512]);
  __syncthreads();

  int buf = 0;
  for(int ci = 0; ci < 16; ci++){
    int k0 = ci*64;
    if(ci < 15){
      gll16(gsrc0 + k0 + 64, &Asm[buf^1][(2*wv)*512]);
      gll16(gsrc1 + k0 + 64, &Asm[buf^1][(2*wv+1)*512]);
    }
    #pragma unroll
    for(int ks = 0; ks < 2; ks++){
      bf16x8 a[4];
      #pragma unroll
      for(int rf = 0; rf < 4; rf++){
        int row = rf*16 + fr;
        int slot = (ks*4 + kg) ^ (row & 7);
        a[rf] = *(const bf16x8*)&Asm[buf][row*64 + slot*8];
      }
      #pragma unroll
      for(int nf = 0; nf < 2; nf++){
        int col = wv*32 + nf*16 + fr;
        bf16x8 b = *(const bf16x8*)&Wb1[(size_t)col*1024 + k0 + ks*32 + kg*8];
        #pragma unroll
        for(int rf = 0; rf < 4; rf++)
          acc[rf][nf] = __builtin_amdgcn_mfma_f32_16x16x32_bf16(a[rf], b, acc[rf][nf], 0, 0, 0);
      }
    }
    __syncthreads();
    buf ^= 1;
  }

  #pragma unroll
  for(int rf = 0; rf < 4; rf++)
    #pragma unroll
    for(int nf = 0; nf < 2; nf++)
      #pragma unroll
      for(int q = 0; q < 4; q++)
        UV[(size_t)(mb + rf*16 + kg*4 + q)*128 + wv*32 + nf*16 + fr] = acc[rf][nf][q];
}

// ---------- kL2bi: bimodal layer-2 + mid store + y1-bi + stats partials ----------
// grid (NB/16, 4): same shapes as R9 kL2v5<3,0>, plus per-slab stats partial pass.
__global__ __launch_bounds__(256) void kL2bi(
    const float* __restrict__ UV1, const u16* __restrict__ xb,
    const u16* __restrict__ W2T, const u16* __restrict__ WpT,
    const float* __restrict__ b1, const float* __restrict__ b2,
    const float* __restrict__ stats, u16* __restrict__ Fcat,
    float* __restrict__ y1g, float* __restrict__ spart)
{
  __shared__ u16 Tsm[3][16][64];
  __shared__ u16 Osm[4][16][264];
  __shared__ float stro[16][15];
  int tid = threadIdx.x;
  int wv = tid >> 6, lane = tid & 63;
  int fr = lane & 15, kg = lane >> 4;
  int Rb = blockIdx.x * 16;
  int slab = blockIdx.y;

  if(tid < 240){
    int rr = tid / 15, c = tid - rr*15;
    stro[rr][c] = stats[(size_t)(Rb + rr)*24 + c];
  }
  for(int i = tid; i < 384; i += 256){
    int g = i & 7, r = (i >> 3) & 15, p = i >> 7;
    int R = Rb + r;
    int up = (p == 2) ? 1 : 0;
    int vp = (p == 0) ? 1 : 2;
    const float* Up = UV1 + (size_t)(3*R + up)*128 + g*8;
    const float* Vp = UV1 + (size_t)(3*R + vp)*128 + 64 + g*8;
    float4 u0 = *(const float4*)Up, u1 = *(const float4*)(Up+4);
    float4 v0 = *(const float4*)Vp, v1 = *(const float4*)(Vp+4);
    float4 bb0 = *(const float4*)(b1 + g*8), bb1 = *(const float4*)(b1 + g*8 + 4);
    float t[8] = {u0.x+v0.x+bb0.x, u0.y+v0.y+bb0.y, u0.z+v0.z+bb0.z, u0.w+v0.w+bb0.w,
                  u1.x+v1.x+bb1.x, u1.y+v1.y+bb1.y, u1.z+v1.z+bb1.z, u1.w+v1.w+bb1.w};
    bf16x8 o;
    #pragma unroll
    for(int j = 0; j < 8; j++){
      float tv = t[j] > 0.f ? t[j] : 0.2f*t[j];
      o[j] = (short)f2bf_tr(tv);
    }
    *(bf16x8*)&Tsm[p][r][(g ^ (r & 7))*8] = o;
  }
  __syncthreads();

  f32x4 acc[3][4];
  #pragma unroll
  for(int p = 0; p < 3; p++)
    #pragma unroll
    for(int cf = 0; cf < 4; cf++) acc[p][cf] = (f32x4){0,0,0,0};
  #pragma unroll
  for(int ks = 0; ks < 2; ks++){
    bf16x8 a[3];
    #pragma unroll
    for(int p = 0; p < 3; p++)
      a[p] = *(const bf16x8*)&Tsm[p][fr][(((ks<<2)+kg) ^ (fr & 7))*8];
    #pragma unroll
    for(int cf = 0; cf < 4; cf++){
      bf16x8 b = *(const bf16x8*)&W2T[(size_t)(slab*256 + wv*64 + cf*16 + fr)*64
                                      + ks*32 + kg*8];
      #pragma unroll
      for(int p = 0; p < 3; p++)
        acc[p][cf] = __builtin_amdgcn_mfma_f32_16x16x32_bf16(a[p], b, acc[p][cf], 0, 0, 0);
    }
  }

  #pragma unroll
  for(int q = 0; q < 4; q++){
    int row = kg*4 + q;
    #pragma unroll
    for(int cf = 0; cf < 4; cf++){
      int cloc = wv*64 + cf*16 + fr;
      float b2c = b2[slab*256 + cloc];
      float sm = 0.f;
      #pragma unroll
      for(int p = 0; p < 3; p++){
        float g = stro[row][3+p] * fast_tanh(acc[p][cf][q] + b2c);
        float val = g > 0.f ? g : 0.01f*g;
        Osm[p][row][cloc] = f2bf(val);
        sm += val;
      }
      Osm[3][row][cloc] = f2bf_tr(sm);
    }
  }
  __syncthreads();

  // 4a: coalesced mid store-out
  {
    int orow = tid >> 4, oc16 = (tid & 15) * 16;
    #pragma unroll
    for(int p = 0; p < 3; p++){
      bf16x8 o0 = *(const bf16x8*)&Osm[p][orow][oc16];
      bf16x8 o1 = *(const bf16x8*)&Osm[p][orow][oc16 + 8];
      size_t off = (size_t)(Rb + orow)*KF + (size_t)(1+p)*1024 + slab*256 + oc16;
      *(bf16x8*)&Fcat[off]     = o0;
      *(bf16x8*)&Fcat[off + 8] = o1;
    }
  }

  // 4b: y1 bimodal contribution (K-slice) -> atomicAdd
  {
    const u16* bptr = WpT + (size_t)(wv*16 + fr)*KF + 1024 + slab*256 + kg*8;
    f32x4 accy = (f32x4){0,0,0,0};
    #pragma unroll
    for(int kq = 0; kq < 4; kq++)
      #pragma unroll
      for(int ks = 0; ks < 2; ks++){
        bf16x8 a = *(const bf16x8*)&Osm[3][fr][kq*64 + ks*32 + kg*8];
        bf16x8 b = *(const bf16x8*)(bptr + kq*64 + ks*32);
        accy = __builtin_amdgcn_mfma_f32_16x16x32_bf16(a, b, accy, 0, 0, 0);
      }
    #pragma unroll
    for(int q = 0; q < 4; q++)
      atomicAdd(&y1g[(size_t)(Rb + kg*4 + q)*64 + wv*16 + fr], accy[q]);
  }

  // 4c: stats partials for this 256-col slab (replaces k3s)
  {
    int srow = tid >> 4, sc0 = (tid & 15) * 16;
    float mAr = stro[srow][9], mVr = stro[srow][11], mLr = stro[srow][13];
    size_t xbase = (size_t)3*(Rb + srow)*DD + slab*256;
    const u32* xa1 = (const u32*)(xb + xbase);
    const u32* xv1 = (const u32*)(xb + xbase + DD);
    const u32* xl1 = (const u32*)(xb + xbase + 2*DD);
    float SP[9] = {0,0,0,0,0,0,0,0,0};
    #pragma unroll
    for(int j = 0; j < 8; j++){
      u32 oav = *(const u32*)&Osm[0][srow][sc0 + 2*j];
      u32 oal = *(const u32*)&Osm[1][srow][sc0 + 2*j];
      u32 ovl = *(const u32*)&Osm[2][srow][sc0 + 2*j];
      u32 wa = xa1[(sc0>>1)+j], wvv = xv1[(sc0>>1)+j], wl = xl1[(sc0>>1)+j];
      float eavx = __expf(bf2f((u16)oav)), eavy = __expf(bf2f((u16)(oav>>16)));
      float ealx = __expf(bf2f((u16)oal)), ealy = __expf(bf2f((u16)(oal>>16)));
      float evlx = __expf(bf2f((u16)ovl)), evly = __expf(bf2f((u16)(ovl>>16)));
      float eax = __expf(bf2f((u16)wa)-mAr),  eay = __expf(bf2f((u16)(wa>>16))-mAr);
      float evx = __expf(bf2f((u16)wvv)-mVr), evy = __expf(bf2f((u16)(wvv>>16))-mVr);
      float elx = __expf(bf2f((u16)wl)-mLr),  ely = __expf(bf2f((u16)(wl>>16))-mLr);
      SP[0] += eavx+eavy; SP[1] += ealx+ealy; SP[2] += evlx+evly;
      SP[3] += eavx*evlx + eavy*evly;
      SP[4] += eavx*ealx + eavy*ealy;
      SP[5] += ealx*evlx + ealy*evly;
      SP[6] += eavx*elx + eavy*ely;
      SP[7] += ealx*evx + ealy*evy;
      SP[8] += evlx*eax + evly*eay;
    }
    #pragma unroll
    for(int s = 0; s < 9; s++){
      SP[s] += __shfl_xor(SP[s], 1);
      SP[s] += __shfl_xor(SP[s], 2);
      SP[s] += __shfl_xor(SP[s], 4);
      SP[s] += __shfl_xor(SP[s], 8);
    }
    if((tid & 15) == 0){
      float* spr = spart + (size_t)(Rb + srow)*9;
      #pragma unroll
      for(int s = 0; s < 9; s++) atomicAdd(&spr[s], SP[s]);
    }
  }
}

// ---------- kTRIv2: w_tri finalize + trimodal layer-2 + y1-tri ----------
// grid (NB/16, 4): same shapes as R9 kL2v5<6,1>.
__global__ __launch_bounds__(256) void kTRIv2(
    const float* __restrict__ UV2, const float* __restrict__ UV1,
    const u16* __restrict__ W2T, const u16* __restrict__ WpT,
    const float* __restrict__ b1, const float* __restrict__ b2,
    const float* __restrict__ stats, const float* __restrict__ spart,
    float* __restrict__ tw, float* __restrict__ y1g)
{
  __shared__ u16 Tsm[6][16][64];
  __shared__ u16 Osm[16][264];
  __shared__ float stw[16][6];
  int tid = threadIdx.x;
  int wv = tid >> 6, lane = tid & 63;
  int fr = lane & 15, kg = lane >> 4;
  int Rb = blockIdx.x * 16;
  int slab = blockIdx.y;

  // phase 0: w_tri from stats + spart (per row)
  if(tid < 16){
    int R = Rb + tid;
    const float* st = stats + (size_t)R*24;
    const float* sp = spart + (size_t)R*9;
    float sa=st[0], sv=st[1], sl=st[2];
    float sav=st[6], sal=st[7], svl=st[8];
    float Sa=st[10], Sv=st[12], Sl=st[14];
    float s0=sp[0], s1=sp[1], s2=sp[2];
    float d1 = sp[3]/(s0*s2), d2 = sp[4]/(s0*s1), d3 = sp[5]/(s1*s2);
    float d4 = sp[6]/(s0*Sl), d5 = sp[7]/(s1*Sv), d6 = sp[8]/(s2*Sa);
    float t0 = (sav+svl)/(d1+0.5f);
    float t1 = (sav+sal)/(d2+0.5f);
    float t2 = (sal+svl)/(d3+0.5f);
    float t3 = (sav+sl)/(d4+0.5f);
    float t4 = (sal+sv)/(d5+0.5f);
    float t5 = (sa+svl)/(d6+0.5f);
    float mx = fmaxf(fmaxf(fmaxf(t0,t1),fmaxf(t2,t3)),fmaxf(t4,t5));
    float g0=__expf(t0-mx),g1=__expf(t1-mx),g2=__expf(t2-mx);
    float g3=__expf(t3-mx),g4=__expf(t4-mx),g5=__expf(t5-mx);
    float gs = g0+g1+g2+g3+g4+g5;
    float wt[6] = {g0/gs,g1/gs,g2/gs,g3/gs,g4/gs,g5/gs};
    #pragma unroll
    for(int p = 0; p < 6; p++) stw[tid][p] = wt[p];
    if(slab == 0){
      float* twr = tw + (size_t)R*12;
      #pragma unroll
      for(int p = 0; p < 6; p++) twr[6+p] = wt[p];
    }
  }
  for(int i = tid; i < 768; i += 256){
    int g = i & 7, r = (i >> 3) & 15, p = i >> 7;
    int R = Rb + r;
    int up = (0x210200 >> (p*4)) & 15;
    int vp = (0x012112 >> (p*4)) & 15;
    const float* VB = (p < 3) ? UV2 : UV1;
    const float* Up = UV2 + (size_t)(3*R + up)*128 + g*8;
    const float* Vp = VB  + (size_t)(3*R + vp)*128 + 64 + g*8;
    float4 u0 = *(const float4*)Up, u1 = *(const float4*)(Up+4);
    float4 v0 = *(const float4*)Vp, v1 = *(const float4*)(Vp+4);
    float4 bb0 = *(const float4*)(b1 + g*8), bb1 = *(const float4*)(b1 + g*8 + 4);
    float t[8] = {u0.x+v0.x+bb0.x, u0.y+v0.y+bb0.y, u0.z+v0.z+bb0.z, u0.w+v0.w+bb0.w,
                  u1.x+v1.x+bb1.x, u1.y+v1.y+bb1.y, u1.z+v1.z+bb1.z, u1.w+v1.w+bb1.w};
    bf16x8 o;
    #pragma unroll
    for(int j = 0; j < 8; j++){
      float tv = t[j] > 0.f ? t[j] : 0.2f*t[j];
      o[j] = (short)f2bf_tr(tv);
    }
    *(bf16x8*)&Tsm[p][r][(g ^ (r & 7))*8] = o;
  }
  __syncthreads();

  f32x4 acc[6][4];
  #pragma unroll
  for(int p = 0; p < 6; p++)
    #pragma unroll
    for(int cf = 0; cf < 4; cf++) acc[p][cf] = (f32x4){0,0,0,0};
  #pragma unroll
  for(int ks = 0; ks < 2; ks++){
    bf16x8 a[6];
    #pragma unroll
    for(int p = 0; p < 6; p++)
      a[p] = *(const bf16x8*)&Tsm[p][fr][(((ks<<2)+kg) ^ (fr & 7))*8];
    #pragma unroll
    for(int cf = 0; cf < 4; cf++){
      bf16x8 b = *(const bf16x8*)&W2T[(size_t)(slab*256 + wv*64 + cf*16 + fr)*64
                                      + ks*32 + kg*8];
      #pragma unroll
      for(int p = 0; p < 6; p++)
        acc[p][cf] = __builtin_amdgcn_mfma_f32_16x16x32_bf16(a[p], b, acc[p][cf], 0, 0, 0);
    }
  }

  #pragma unroll
  for(int q = 0; q < 4; q++){
    int row = kg*4 + q;
    #pragma unroll
    for(int cf = 0; cf < 4; cf++){
      int cloc = wv*64 + cf*16 + fr;
      float b2c = b2[slab*256 + cloc];
      float s = 0.f;
      #pragma unroll
      for(int p = 0; p < 6; p++){
        float g = stw[row][p] * fast_tanh(acc[p][cf][q] + b2c);
        s += g > 0.f ? g : 0.01f*g;
      }
      Osm[row][cloc] = f2bf_tr(s * (1.0f/6.0f));
    }
  }
  __syncthreads();

  {
    const u16* bptr = WpT + (size_t)(wv*16 + fr)*KF + 4096 + slab*256 + kg*8;
    f32x4 accy = (f32x4){0,0,0,0};
    #pragma unroll
    for(int kq = 0; kq < 4; kq++)
      #pragma unroll
      for(int ks = 0; ks < 2; ks++){
        bf16x8 a = *(const bf16x8*)&Osm[fr][kq*64 + ks*32 + kg*8];
        bf16x8 b = *(const bf16x8*)(bptr + kq*64 + ks*32);
        accy = __builtin_amdgcn_mfma_f32_16x16x32_bf16(a, b, accy, 0, 0, 0);
      }
    #pragma unroll
    for(int q = 0; q < 4; q++)
      atomicAdd(&y1g[(size_t)(Rb + kg*4 + q)*64 + wv*16 + fr], accy[q]);
  }
}

// ---------- K6 v5: uni GEMM (K=1024) + y1g + MLP tail ----------
__global__ __launch_bounds__(256) void k6v5(
    const u16* __restrict__ uniB, const u16* __restrict__ WpT,
    const float* __restrict__ y1g, const float* __restrict__ bp,
    const float* __restrict__ l2W, const float* __restrict__ l2b,
    const float* __restrict__ l3W, const float* __restrict__ l3b,
    float* __restrict__ y2out)
{
  __shared__ __align__(16) char smem[37952];
  u16*  Asm = (u16*)smem;
  float* W2s = (float*)(smem + 16384);
  float* W3s = (float*)(smem + 16384 + 12800);
  float* Ys  = (float*)smem;
  float* Ys2 = (float*)(smem + 16384 + 12800 + 1600);

  int tid = threadIdx.x;
  int wv = tid >> 6, lane = tid & 63;
  int fr = lane & 15, kg = lane >> 4;
  int rb = blockIdx.x * 32;

  for(int t = tid; t < 3200; t += 256){
    int c = t & 63;
    W2s[t] = (c < 50) ? l2W[(t >> 6)*50 + c] : 0.f;
  }
  for(int t = tid; t < 400; t += 256) W3s[t] = l3W[t];

  int r8 = lane >> 3, pp = lane & 7;
  int sp = pp ^ r8;
  const u16* gsrc = uniB + (size_t)(rb + wv*8 + r8)*DD + sp*8;
  const u16* bptr = WpT  + (size_t)(wv*16 + fr)*KF + kg*8;

  f32x4 acc[2];
  acc[0] = (f32x4){0.f,0.f,0.f,0.f};
  acc[1] = (f32x4){0.f,0.f,0.f,0.f};

  gll16(gsrc,      &Asm[wv*1024]);
  gll16(gsrc + 64, &Asm[wv*1024 + 512]);
  __syncthreads();

  int buf = 0;
  for(int ci = 0; ci < 8; ci++){
    int k0 = ci*128;
    if(ci < 7){
      gll16(gsrc + k0 + 128, &Asm[(buf^1)*4096 + wv*1024]);
      gll16(gsrc + k0 + 192, &Asm[(buf^1)*4096 + wv*1024 + 512]);
    }
    #pragma unroll
    for(int kh = 0; kh < 2; kh++){
      #pragma unroll
      for(int ks = 0; ks < 2; ks++){
        bf16x8 b = *(const bf16x8*)(bptr + k0 + kh*64 + ks*32);
        #pragma unroll
        for(int rf = 0; rf < 2; rf++){
          int row = rf*16 + fr;
          int slot = ((ks<<2) + kg) ^ (row & 7);
          bf16x8 a = *(const bf16x8*)&Asm[buf*4096 + (row>>3)*1024 + kh*512
                                          + (row & 7)*64 + slot*8];
          acc[rf] = __builtin_amdgcn_mfma_f32_16x16x32_bf16(a, b, acc[rf], 0, 0, 0);
        }
      }
    }
    __syncthreads();
    buf ^= 1;
  }

  {
    int col = wv*16 + fr;
    float bpc = bp[col];
    #pragma unroll
    for(int rf = 0; rf < 2; rf++)
      #pragma unroll
      for(int q = 0; q < 4; q++){
        int row = rf*16 + kg*4 + q;
        if(col < 50){
          float z = acc[rf][q] + y1g[(size_t)(rb + row)*64 + col] + bpc;
          Ys[row*56 + col] = fast_tanh(z);
        }
      }
  }
  __syncthreads();

  {
    int r = tid >> 3, cg = (tid & 7) * 7;
    float a2[7] = {0,0,0,0,0,0,0};
    for(int k = 0; k < 50; k++){
      float yv = Ys[r*56 + k];
      #pragma unroll
      for(int c = 0; c < 7; c++) a2[c] = fmaf(yv, W2s[k*64 + cg + c], a2[c]);
    }
    #pragma unroll
    for(int c = 0; c < 7; c++){
      int cc = cg + c;
      if(cc < 50) Ys2[r*56 + cc] = fast_tanh(a2[c] + l2b[cc]);
    }
  }
  __syncthreads();

  {
    int r = tid >> 3, c = tid & 7;
    float z = l3b[c];
    for(int k = 0; k < 50; k++) z = fmaf(Ys2[r*56 + k], W3s[k*8 + c], z);
    float m = z;
    m = fmaxf(m, __shfl_xor(m, 1));
    m = fmaxf(m, __shfl_xor(m, 2));
    m = fmaxf(m, __shfl_xor(m, 4));
    float e = __expf(z - m);
    float s = e;
    s += __shfl_xor(s, 1); s += __shfl_xor(s, 2); s += __shfl_xor(s, 4);
    y2out[(size_t)(rb + r)*8 + c] = e / s;
  }
}

// ---------- launch ----------
extern "C" void kernel_launch(void* const* d_in, const int* in_sizes, int n_in,
                              void* d_out, int out_size, void* d_ws, size_t ws_size,
                              hipStream_t stream)
{
  (void)in_sizes; (void)n_in; (void)out_size; (void)ws_size;
  const float* x    = (const float*)d_in[0];
  const float* attW = (const float*)d_in[1];
  const float* attb = (const float*)d_in[2];
  const float* gfW1 = (const float*)d_in[3];
  const float* gfb1 = (const float*)d_in[4];
  const float* gfW2 = (const float*)d_in[5];
  const float* gfb2 = (const float*)d_in[6];
  const float* bng  = (const float*)d_in[7];
  const float* bnb  = (const float*)d_in[8];
  const float* l1W  = (const float*)d_in[9];
  const float* l1b  = (const float*)d_in[10];
  const float* l2W  = (const float*)d_in[11];
  const float* l2b  = (const float*)d_in[12];
  const float* l3W  = (const float*)d_in[13];
  const float* l3b  = (const float*)d_in[14];

  float* out = (float*)d_out;
  float* tw  = out + (size_t)NB*8;

  // workspace layout
  float* ws    = (float*)d_ws;
  float* stats = ws;                               // NB*24 f32
  float* UV1   = stats + (size_t)NB*24;            // 3*NB*128 f32
  float* UV2   = UV1 + (size_t)3*NB*128;           // 3*NB*128 f32
  float* bp    = UV2 + (size_t)3*NB*128;           // 64 f32
  float* y1g   = bp + 64;                          // NB*64 f32
  float* spart = y1g + (size_t)NB*64;              // NB*9 f32
  u16* WpT     = (u16*)(spart + (size_t)NB*9);     // 64*KF bf16
  u16* Wb1     = WpT + (size_t)64*KF;              // 128*1024 bf16
  u16* W2T     = Wb1 + (size_t)128*1024;           // 1024*64 bf16
  u16* Fcat    = W2T + (size_t)1024*64;            // NB*KF bf16 (mid planes)
  u16* xb      = Fcat + (size_t)NB*KF;             // 3*NB*1024 bf16
  u16* uniB    = xb + (size_t)3*NB*DD;             // NB*1024 bf16

  kpre<<<dim3(3217), dim3(256), 0, stream>>>(gfW1, gfW2, bng, bnb, l1W, l1b,
                                             Wb1, W2T, WpT, bp, y1g, spart);
  k1_stats<<<dim3(NB/4), dim3(256), 0, stream>>>(x, attW, attb, stats, uniB, xb, tw);
  kg1v3<0><<<dim3(3*NB/64), dim3(256), 0, stream>>>(xb, Wb1, UV1);
  kL2bi<<<dim3(NB/16, 4), dim3(256), 0, stream>>>(UV1, xb, W2T, WpT,
                                                  gfb1, gfb2, stats, Fcat, y1g, spart);
  kg1v3<1><<<dim3(3*NB/64), dim3(256), 0, stream>>>(Fcat, Wb1, UV2);
  kTRIv2<<<dim3(NB/16, 4), dim3(256), 0, stream>>>(UV2, UV1, W2T, WpT,
                                                   gfb1, gfb2, stats, spart, tw, y1g);
  k6v5<<<dim3(NB/32), dim3(256), 0, stream>>>(uniB, WpT, y1g, bp,
                                              l2W, l2b, l3W, l3b, out);
}